// Round 7
// baseline (256.267 us; speedup 1.0000x reference)
//
#include <hip/hip_runtime.h>
#include <hip/hip_bf16.h>
#include <hip/hip_fp16.h>

constexpr int N_   = 50000;
constexpr int E_   = 800000;
constexpr int G_   = 256;
constexpr int IN_  = 64;
constexpr int H_   = 8;
constexpr int OUT_ = 128;   // H*C
constexpr float NEG_SLOPE = 0.2f;
constexpr int NB_  = (N_ + 255) / 256;   // 196 scan blocks

// ---- workspace layout (byte offsets, all 256B-aligned) ----
constexpr size_t OFF_X     = 0;                                  // [N,128] f16 (gather table)
constexpr size_t OFF_ASRC  = OFF_X     + (size_t)N_*OUT_*4;      // [N,8]  f32
constexpr size_t OFF_ADST  = OFF_ASRC  + (size_t)N_*H_*4;        // [N,8]  f32
constexpr size_t OFF_EMB   = OFF_ADST  + (size_t)N_*H_*4;        // [N,128] f32
constexpr size_t OFF_GSUM  = OFF_EMB   + (size_t)N_*OUT_*4;      // [G,128] f32 (zeroed)
constexpr size_t OFF_DEG   = OFF_GSUM  + (size_t)G_*OUT_*4;      // [N] int (zeroed)
constexpr size_t OFF_GEMB  = OFF_DEG   + (size_t)N_*4;           // [G,128] f32 (unused now)
constexpr size_t OFF_GCNT  = OFF_GEMB  + (size_t)G_*OUT_*4;      // [G] f32 (unused now)
constexpr size_t OFF_ROWS  = OFF_GCNT  + (size_t)G_*4 + 252;     // [N+1] int
constexpr size_t OFF_CUR   = OFF_ROWS  + (size_t)(N_+1)*4 + 252; // [N] int
constexpr size_t OFF_EIDX  = OFF_CUR   + (size_t)N_*4;           // [E] int (src per slot)
constexpr size_t OFF_BSUM  = OFF_EIDX  + (size_t)E_*4;           // [NB] int
constexpr size_t OFF_BOFF  = OFF_BSUM  + (size_t)NB_*4 + 240;    // [NB] int
constexpr size_t OFF_GPART = OFF_BOFF  + (size_t)NB_*4 + 240;    // [G,128] f32
constexpr size_t ZERO_BEG  = OFF_GSUM;
constexpr size_t ZERO_LEN  = OFF_GEMB - OFF_GSUM;                // gsum + deg

// K1: x = feat @ W_gat (f16 out); a_src/a_dst per-head dots. 16 nodes/block.
__global__ void k_transform(const float* __restrict__ feat, const float* __restrict__ Wg,
                            const float* __restrict__ att_s, const float* __restrict__ att_d,
                            __half* __restrict__ xh, float* __restrict__ asrc,
                            float* __restrict__ adst) {
    const int base = blockIdx.x * 16;
    const int j    = threadIdx.x & 127;
    const int half = threadIdx.x >> 7;

    __shared__ float f[16][IN_];
    for (int t = threadIdx.x; t < 16 * IN_; t += 256) {
        int ni = t >> 6, k = t & 63;
        f[ni][k] = feat[(size_t)(base + ni) * IN_ + k];
    }
    __syncthreads();

    float acc[8];
#pragma unroll
    for (int i = 0; i < 8; ++i) acc[i] = 0.f;
    for (int k = 0; k < IN_; ++k) {
        float w = Wg[k * OUT_ + j];
#pragma unroll
        for (int i = 0; i < 8; ++i) acc[i] += f[half * 8 + i][k] * w;
    }
    const float aw_s = att_s[j];
    const float aw_d = att_d[j];
#pragma unroll
    for (int i = 0; i < 8; ++i) {
        int n = base + half * 8 + i;
        xh[(size_t)n * OUT_ + j] = __float2half(acc[i]);
        float ps = acc[i] * aw_s;
        float pd = acc[i] * aw_d;
#pragma unroll
        for (int m = 8; m >= 1; m >>= 1) {
            ps += __shfl_xor(ps, m, 16);
            pd += __shfl_xor(pd, m, 16);
        }
        if ((j & 15) == 0) {
            asrc[n * H_ + (j >> 4)] = ps;
            adst[n * H_ + (j >> 4)] = pd;
        }
    }
}

// K2a: in-degree histogram.
__global__ void k_hist(const int* __restrict__ dst, int* __restrict__ deg) {
    int e = blockIdx.x * 256 + threadIdx.x;
    if (e < E_) atomicAdd(&deg[dst[e]], 1);
}

// K2b-1: per-block sums of deg (256 elements per block).
__global__ void k_blocksum(const int* __restrict__ deg, int* __restrict__ bsum) {
    int i = blockIdx.x * 256 + threadIdx.x;
    int v = (i < N_) ? deg[i] : 0;
#pragma unroll
    for (int m = 32; m >= 1; m >>= 1) v += __shfl_xor(v, m, 64);
    __shared__ int ws[4];
    if ((threadIdx.x & 63) == 0) ws[threadIdx.x >> 6] = v;
    __syncthreads();
    if (threadIdx.x == 0) bsum[blockIdx.x] = ws[0] + ws[1] + ws[2] + ws[3];
}

// K2b-2: exclusive scan of the NB block sums (one block).
__global__ void k_scanb(const int* __restrict__ bsum, int* __restrict__ boff) {
    __shared__ int s[256];
    int t = threadIdx.x;
    int v = (t < NB_) ? bsum[t] : 0;
    s[t] = v;
    __syncthreads();
    for (int off = 1; off < 256; off <<= 1) {
        int u = (t >= off) ? s[t - off] : 0;
        __syncthreads();
        s[t] += u;
        __syncthreads();
    }
    if (t < NB_) boff[t] = s[t] - v;   // exclusive
}

// K2b-3: block-local exclusive scan + block offset -> rowstart, cursor.
__global__ void k_scanfin(const int* __restrict__ deg, const int* __restrict__ boff,
                          int* __restrict__ rowstart, int* __restrict__ cursor) {
    __shared__ int s[256];
    int t = threadIdx.x;
    int i = blockIdx.x * 256 + t;
    int v = (i < N_) ? deg[i] : 0;
    s[t] = v;
    __syncthreads();
    for (int off = 1; off < 256; off <<= 1) {
        int u = (t >= off) ? s[t - off] : 0;
        __syncthreads();
        s[t] += u;
        __syncthreads();
    }
    if (i < N_) {
        int r = boff[blockIdx.x] + s[t] - v;
        rowstart[i] = r;
        cursor[i]   = r;
    }
    if (i == N_ - 1) rowstart[N_] = E_;
}

// K2c: scatter src indices into dst-grouped buckets.
__global__ void k_scatter(const int* __restrict__ src, const int* __restrict__ dst,
                          int* __restrict__ cursor, int* __restrict__ eidx) {
    int e = blockIdx.x * 256 + threadIdx.x;
    if (e < E_) {
        int pos = atomicAdd(&cursor[dst[e]], 1);
        eidx[pos] = src[e];
    }
}

// K3: CSR aggregation, one wave per dst. 8-edge tiles: lane (s,h)=(l&7,l>>3)
// computes ONE weight covering all (edge,head) pairs; shfl-broadcast to the
// channel-owning lanes. Fused self-loop + softmax-norm + bias + ELU.
__global__ void k_agg(const int* __restrict__ rowstart, const int* __restrict__ eidx,
                      const __half* __restrict__ xh, const float* __restrict__ asrc,
                      const float* __restrict__ adst, const float* __restrict__ bias,
                      float* __restrict__ emb) {
    const int dn   = blockIdx.x * 4 + (threadIdx.x >> 6);   // wave-uniform
    const int lane = threadIdx.x & 63;
    const int h    = lane >> 3;        // head (both roles)
    const int slot = lane & 7;         // edge slot (weight role)
    const int grp  = lane & ~7;        // first lane of this head group
    const float adst_h = adst[dn * H_ + h];

    const int beg = rowstart[dn];
    const int end = rowstart[dn + 1];
    const uint choff = (uint)lane * 2;

    float ax = 0.f, ay = 0.f, sw = 0.f;
    for (int i = beg; i < end; i += 8) {
        const int nedge = end - i;     // >=1; clamp at 8 via breaks
        int   esn = 0;
        float w   = 0.f;
        if (slot < nedge) {
            esn = eidx[i + slot];
            float al = asrc[(uint)esn * H_ + h] + adst_h;
            al = (al > 0.f) ? al : NEG_SLOPE * al;
            w = __expf(al);
        }
#pragma unroll
        for (int s = 0; s < 8; ++s) {
            if (s >= nedge) break;
            float ws = __shfl(w,   grp + s, 64);
            int   sn = __shfl(esn, grp + s, 64);
            __half2 xv = *(const __half2*)(xh + ((uint)sn * OUT_ + choff));
            float2 fv = __half22float2(xv);
            ax = fmaf(ws, fv.x, ax);
            ay = fmaf(ws, fv.y, ay);
            sw += ws;
        }
    }
    // self-loop
    {
        float al = asrc[(uint)dn * H_ + h] + adst_h;
        al = (al > 0.f) ? al : NEG_SLOPE * al;
        float w = __expf(al);
        __half2 xv = *(const __half2*)(xh + ((uint)dn * OUT_ + choff));
        float2 fv = __half22float2(xv);
        ax = fmaf(w, fv.x, ax);
        ay = fmaf(w, fv.y, ay);
        sw += w;
    }
    float ox = ax / sw + bias[lane * 2];
    float oy = ay / sw + bias[lane * 2 + 1];
    ox = (ox > 0.f) ? ox : expm1f(ox);
    oy = (oy > 0.f) ? oy : expm1f(oy);
    *(float2*)&emb[(size_t)dn * OUT_ + lane * 2] = make_float2(ox, oy);
}

// K5: mean-pool numerator. 32 nodes/block; run-length accumulate (batch sorted).
__global__ void k_pool(const float* __restrict__ emb, const int* __restrict__ batch,
                       float* __restrict__ gsum) {
    int j = threadIdx.x & 127;
    int half = threadIdx.x >> 7;
    int base = blockIdx.x * 32 + half * 16;
    float run = 0.f;
    int gcur = -1;
    for (int i = 0; i < 16; ++i) {
        int n = base + i;
        if (n >= N_) break;
        int g = batch[n];
        if (g != gcur) {
            if (gcur >= 0) unsafeAtomicAdd(&gsum[gcur * OUT_ + j], run);
            gcur = g; run = 0.f;
        }
        run += emb[(size_t)n * OUT_ + j];
    }
    if (gcur >= 0) unsafeAtomicAdd(&gsum[gcur * OUT_ + j], run);
}

// K6: fused per-graph: count (binary search), gemb = gsum/cnt -> output,
// gpart = gemb @ W1b + b1. One block per graph, 128 threads.
__global__ void k_graph(const int* __restrict__ batch, const float* __restrict__ gsum,
                        const float* __restrict__ W1, const float* __restrict__ b1,
                        float* __restrict__ outg, float* __restrict__ gpart) {
    const int g = blockIdx.x;
    const int j = threadIdx.x;   // 128
    __shared__ float ge[128];
    __shared__ int cnt_s;
    if (j == 0) {
        int lo = 0, hi = N_;
        while (lo < hi) { int m = (lo + hi) >> 1; if (batch[m] < g) lo = m + 1; else hi = m; }
        int start = lo;
        lo = 0; hi = N_;
        while (lo < hi) { int m = (lo + hi) >> 1; if (batch[m] <= g) lo = m + 1; else hi = m; }
        cnt_s = lo - start;
    }
    __syncthreads();
    float v = gsum[g * 128 + j] / fmaxf((float)cnt_s, 1.f);
    ge[j] = v;
    outg[g * 128 + j] = v;
    __syncthreads();
    float s = b1[j];
    const float* w = W1 + (size_t)128 * 128 + j;
    for (int k = 0; k < 128; ++k) s = fmaf(ge[k], w[(size_t)k * 128], s);
    gpart[g * 128 + j] = s;
}

// K7: decoder GEMM: h=relu(emb@W1a + gpart[batch]); scores=h@W2+b2.
// 64 nodes/block, 256 threads, thread tile = 8 nodes x 4 j.
__global__ __launch_bounds__(256) void k_dec2(const float* __restrict__ emb,
                                              const float* __restrict__ gpart,
                                              const int* __restrict__ batch,
                                              const float* __restrict__ W1,
                                              const float* __restrict__ W2,
                                              const float* __restrict__ b2,
                                              float* __restrict__ scores) {
    constexpr int STR = 68;               // row stride (floats), 272B: 16B aligned
    __shared__ float combT[128 * STR];    // 34.8 KB, k-major
    const int base = blockIdx.x * 64;

    for (int idx = threadIdx.x; idx < 64 * 128; idx += 256) {
        int nl = idx >> 7;        // node 0..63
        int k  = idx & 127;       // coalesced along k
        int n  = base + nl;
        combT[k * STR + nl] = (n < N_) ? emb[(size_t)n * 128 + k] : 0.f;
    }
    __syncthreads();

    const int tj = threadIdx.x & 31;   // j block: columns tj*4..tj*4+3
    const int tn = threadIdx.x >> 5;   // node group: nodes tn*8..tn*8+7

    float acc[8][4];
#pragma unroll
    for (int i = 0; i < 8; ++i)
#pragma unroll
        for (int jj = 0; jj < 4; ++jj) acc[i][jj] = 0.f;

    const float* w1p = W1 + tj * 4;
    const float* cb  = combT + tn * 8;
    for (int k = 0; k < 128; ++k) {
        float4 w  = *(const float4*)(w1p + (size_t)k * 128);
        float4 c0 = *(const float4*)(cb + k * STR);
        float4 c1 = *(const float4*)(cb + k * STR + 4);
        float cv[8] = {c0.x, c0.y, c0.z, c0.w, c1.x, c1.y, c1.z, c1.w};
        float wv[4] = {w.x, w.y, w.z, w.w};
#pragma unroll
        for (int i = 0; i < 8; ++i)
#pragma unroll
            for (int jj = 0; jj < 4; ++jj)
                acc[i][jj] = fmaf(cv[i], wv[jj], acc[i][jj]);
    }

    float4 w2v = *(const float4*)(W2 + tj * 4);
    const float w2a[4] = {w2v.x, w2v.y, w2v.z, w2v.w};
    const float b2v = b2[0];

#pragma unroll
    for (int i = 0; i < 8; ++i) {
        int n = base + tn * 8 + i;
        if (n >= N_) continue;
        int g = batch[n];
        float4 gp = *(const float4*)(gpart + (size_t)g * 128 + tj * 4);
        const float gpa[4] = {gp.x, gp.y, gp.z, gp.w};
        float v = 0.f;
#pragma unroll
        for (int jj = 0; jj < 4; ++jj) {
            float h = acc[i][jj] + gpa[jj];
            h = (h > 0.f) ? h : 0.f;
            v = fmaf(h, w2a[jj], v);
        }
#pragma unroll
        for (int m = 16; m >= 1; m >>= 1) v += __shfl_xor(v, m, 64);
        if (tj == 0) scores[n] = v + b2v;
    }
}

extern "C" void kernel_launch(void* const* d_in, const int* in_sizes, int n_in,
                              void* d_out, int out_size, void* d_ws, size_t ws_size,
                              hipStream_t stream) {
    const float* feat   = (const float*)d_in[0];
    const int*   ei     = (const int*)d_in[1];
    const int*   batch  = (const int*)d_in[2];
    const float* Wg     = (const float*)d_in[3];
    const float* att_s  = (const float*)d_in[4];
    const float* att_d  = (const float*)d_in[5];
    const float* bias_g = (const float*)d_in[6];
    const float* W1     = (const float*)d_in[7];
    const float* b1     = (const float*)d_in[8];
    const float* W2     = (const float*)d_in[9];
    const float* b2     = (const float*)d_in[10];
    char*  wsb = (char*)d_ws;
    float* out = (float*)d_out;

    const int* src = ei;        // edge_index[0]
    const int* dst = ei + E_;   // edge_index[1]

    __half* XH   = (__half*)(wsb + OFF_X);
    float* ASRC  = (float*)(wsb + OFF_ASRC);
    float* ADST  = (float*)(wsb + OFF_ADST);
    float* EMB   = (float*)(wsb + OFF_EMB);
    float* GSUM  = (float*)(wsb + OFF_GSUM);
    int*   DEG   = (int*)  (wsb + OFF_DEG);
    int*   ROWS  = (int*)  (wsb + OFF_ROWS);
    int*   CUR   = (int*)  (wsb + OFF_CUR);
    int*   EIDX  = (int*)  (wsb + OFF_EIDX);
    int*   BSUM  = (int*)  (wsb + OFF_BSUM);
    int*   BOFF  = (int*)  (wsb + OFF_BOFF);
    float* GPART = (float*)(wsb + OFF_GPART);

    hipMemsetAsync(wsb + ZERO_BEG, 0, ZERO_LEN, stream);

    k_transform<<<N_ / 16, 256, 0, stream>>>(feat, Wg, att_s, att_d, XH, ASRC, ADST);
    k_hist<<<(E_ + 255) / 256, 256, 0, stream>>>(dst, DEG);
    k_blocksum<<<NB_, 256, 0, stream>>>(DEG, BSUM);
    k_scanb<<<1, 256, 0, stream>>>(BSUM, BOFF);
    k_scanfin<<<NB_, 256, 0, stream>>>(DEG, BOFF, ROWS, CUR);
    k_scatter<<<(E_ + 255) / 256, 256, 0, stream>>>(src, dst, CUR, EIDX);
    k_agg<<<N_ / 4, 256, 0, stream>>>(ROWS, EIDX, XH, ASRC, ADST, bias_g, EMB);
    k_pool<<<(N_ + 31) / 32, 256, 0, stream>>>(EMB, batch, GSUM);
    k_graph<<<G_, 128, 0, stream>>>(batch, GSUM, W1, b1, out + N_, GPART);
    k_dec2<<<(N_ + 63) / 64, 256, 0, stream>>>(EMB, GPART, batch, W1, W2, b2, out);
}

// Round 8
// 214.467 us; speedup vs baseline: 1.1949x; 1.1949x over previous
//
#include <hip/hip_runtime.h>
#include <hip/hip_bf16.h>
#include <hip/hip_fp16.h>

constexpr int N_   = 50000;
constexpr int E_   = 800000;
constexpr int G_   = 256;
constexpr int IN_  = 64;
constexpr int H_   = 8;
constexpr int OUT_ = 128;   // H*C
constexpr float NEG_SLOPE = 0.2f;
constexpr int NB_  = (N_ + 255) / 256;   // 196 scan blocks

typedef _Float16 f16x8 __attribute__((ext_vector_type(8)));
typedef float    f32x4 __attribute__((ext_vector_type(4)));

// ---- workspace layout (byte offsets, all 256B-aligned) ----
// X slot holds [N,128] f16 gather table in its first half and [N,128] f16
// decoder copy of emb in its second half (slot was sized for f32).
constexpr size_t OFF_X     = 0;                                  // [N,128] f16 xh
constexpr size_t OFF_EMBH  = OFF_X     + (size_t)N_*OUT_*2;      // [N,128] f16 emb copy
constexpr size_t OFF_ASRC  = OFF_X     + (size_t)N_*OUT_*4;      // [N,8]  f32
constexpr size_t OFF_ADST  = OFF_ASRC  + (size_t)N_*H_*4;        // [N,8]  f32
constexpr size_t OFF_EMB   = OFF_ADST  + (size_t)N_*H_*4;        // [N,128] f32
constexpr size_t OFF_GSUM  = OFF_EMB   + (size_t)N_*OUT_*4;      // [G,128] f32 (zeroed)
constexpr size_t OFF_DEG   = OFF_GSUM  + (size_t)G_*OUT_*4;      // [N] int (zeroed)
constexpr size_t OFF_WT    = OFF_DEG   + (size_t)N_*4;           // [128,128] f16 W1a^T (in old GEMB slot)
constexpr size_t OFF_GCNT  = OFF_WT    + (size_t)G_*OUT_*4;      // [G] f32 (unused)
constexpr size_t OFF_ROWS  = OFF_GCNT  + (size_t)G_*4 + 252;     // [N+1] int
constexpr size_t OFF_CUR   = OFF_ROWS  + (size_t)(N_+1)*4 + 252; // [N] int
constexpr size_t OFF_EIDX  = OFF_CUR   + (size_t)N_*4;           // [E] int (src per slot)
constexpr size_t OFF_BSUM  = OFF_EIDX  + (size_t)E_*4;           // [NB] int
constexpr size_t OFF_BOFF  = OFF_BSUM  + (size_t)NB_*4 + 240;    // [NB] int
constexpr size_t OFF_GPART = OFF_BOFF  + (size_t)NB_*4 + 240;    // [G,128] f32
constexpr size_t ZERO_BEG  = OFF_GSUM;
constexpr size_t ZERO_LEN  = OFF_WT - OFF_GSUM;                  // gsum + deg

// K1: x = feat @ W_gat (f16 out); a_src/a_dst per-head dots. 16 nodes/block.
__global__ void k_transform(const float* __restrict__ feat, const float* __restrict__ Wg,
                            const float* __restrict__ att_s, const float* __restrict__ att_d,
                            __half* __restrict__ xh, float* __restrict__ asrc,
                            float* __restrict__ adst) {
    const int base = blockIdx.x * 16;
    const int j    = threadIdx.x & 127;
    const int half = threadIdx.x >> 7;

    __shared__ float f[16][IN_];
    for (int t = threadIdx.x; t < 16 * IN_; t += 256) {
        int ni = t >> 6, k = t & 63;
        f[ni][k] = feat[(size_t)(base + ni) * IN_ + k];
    }
    __syncthreads();

    float acc[8];
#pragma unroll
    for (int i = 0; i < 8; ++i) acc[i] = 0.f;
    for (int k = 0; k < IN_; ++k) {
        float w = Wg[k * OUT_ + j];
#pragma unroll
        for (int i = 0; i < 8; ++i) acc[i] += f[half * 8 + i][k] * w;
    }
    const float aw_s = att_s[j];
    const float aw_d = att_d[j];
#pragma unroll
    for (int i = 0; i < 8; ++i) {
        int n = base + half * 8 + i;
        xh[(size_t)n * OUT_ + j] = __float2half(acc[i]);
        float ps = acc[i] * aw_s;
        float pd = acc[i] * aw_d;
#pragma unroll
        for (int m = 8; m >= 1; m >>= 1) {
            ps += __shfl_xor(ps, m, 16);
            pd += __shfl_xor(pd, m, 16);
        }
        if ((j & 15) == 0) {
            asrc[n * H_ + (j >> 4)] = ps;
            adst[n * H_ + (j >> 4)] = pd;
        }
    }
}

// K1b: Wt[j][k] = f16(W1[k][j]) for k<128 (W1a transpose).
__global__ void k_w1t(const float* __restrict__ W1, __half* __restrict__ wt) {
    const int j = blockIdx.x;     // 128
    const int k = threadIdx.x;    // 128
    wt[j * 128 + k] = __float2half(W1[(size_t)k * 128 + j]);
}

// K2a: in-degree histogram.
__global__ void k_hist(const int* __restrict__ dst, int* __restrict__ deg) {
    int e = blockIdx.x * 256 + threadIdx.x;
    if (e < E_) atomicAdd(&deg[dst[e]], 1);
}

// K2b-1: per-block sums of deg (256 elements per block).
__global__ void k_blocksum(const int* __restrict__ deg, int* __restrict__ bsum) {
    int i = blockIdx.x * 256 + threadIdx.x;
    int v = (i < N_) ? deg[i] : 0;
#pragma unroll
    for (int m = 32; m >= 1; m >>= 1) v += __shfl_xor(v, m, 64);
    __shared__ int ws[4];
    if ((threadIdx.x & 63) == 0) ws[threadIdx.x >> 6] = v;
    __syncthreads();
    if (threadIdx.x == 0) bsum[blockIdx.x] = ws[0] + ws[1] + ws[2] + ws[3];
}

// K2b-2: exclusive scan of the NB block sums (one block).
__global__ void k_scanb(const int* __restrict__ bsum, int* __restrict__ boff) {
    __shared__ int s[256];
    int t = threadIdx.x;
    int v = (t < NB_) ? bsum[t] : 0;
    s[t] = v;
    __syncthreads();
    for (int off = 1; off < 256; off <<= 1) {
        int u = (t >= off) ? s[t - off] : 0;
        __syncthreads();
        s[t] += u;
        __syncthreads();
    }
    if (t < NB_) boff[t] = s[t] - v;   // exclusive
}

// K2b-3: block-local exclusive scan + block offset -> rowstart, cursor.
__global__ void k_scanfin(const int* __restrict__ deg, const int* __restrict__ boff,
                          int* __restrict__ rowstart, int* __restrict__ cursor) {
    __shared__ int s[256];
    int t = threadIdx.x;
    int i = blockIdx.x * 256 + t;
    int v = (i < N_) ? deg[i] : 0;
    s[t] = v;
    __syncthreads();
    for (int off = 1; off < 256; off <<= 1) {
        int u = (t >= off) ? s[t - off] : 0;
        __syncthreads();
        s[t] += u;
        __syncthreads();
    }
    if (i < N_) {
        int r = boff[blockIdx.x] + s[t] - v;
        rowstart[i] = r;
        cursor[i]   = r;
    }
    if (i == N_ - 1) rowstart[N_] = E_;
}

// K2c: scatter src indices into dst-grouped buckets.
__global__ void k_scatter(const int* __restrict__ src, const int* __restrict__ dst,
                          int* __restrict__ cursor, int* __restrict__ eidx) {
    int e = blockIdx.x * 256 + threadIdx.x;
    if (e < E_) {
        int pos = atomicAdd(&cursor[dst[e]], 1);
        eidx[pos] = src[e];
    }
}

// K3: CSR aggregation (r6 structure, 4-edge unroll: gather addresses depend
// only on eidx so 4 gathers stay in flight; exp overlaps fetch latency).
__global__ void k_agg(const int* __restrict__ rowstart, const int* __restrict__ eidx,
                      const __half* __restrict__ xh, const float* __restrict__ asrc,
                      const float* __restrict__ adst, const float* __restrict__ bias,
                      float* __restrict__ emb, __half* __restrict__ embh) {
    const int dn   = blockIdx.x * 4 + (threadIdx.x >> 6);   // wave-uniform
    const int lane = threadIdx.x & 63;
    const int h    = lane >> 3;
    const float adst_h = adst[dn * H_ + h];
    const uint choff = (uint)lane * 2;

    const int beg = rowstart[dn];
    const int end = rowstart[dn + 1];

    float ax = 0.f, ay = 0.f, sw = 0.f;
    int i = beg;
    for (; i + 3 < end; i += 4) {
        int s0 = eidx[i];
        int s1 = eidx[i + 1];
        int s2 = eidx[i + 2];
        int s3 = eidx[i + 3];
        __half2 x0 = *(const __half2*)(xh + ((uint)s0 * OUT_ + choff));
        __half2 x1 = *(const __half2*)(xh + ((uint)s1 * OUT_ + choff));
        __half2 x2 = *(const __half2*)(xh + ((uint)s2 * OUT_ + choff));
        __half2 x3 = *(const __half2*)(xh + ((uint)s3 * OUT_ + choff));
        float a0 = asrc[(uint)s0 * H_ + h] + adst_h;
        float a1 = asrc[(uint)s1 * H_ + h] + adst_h;
        float a2 = asrc[(uint)s2 * H_ + h] + adst_h;
        float a3 = asrc[(uint)s3 * H_ + h] + adst_h;
        a0 = (a0 > 0.f) ? a0 : NEG_SLOPE * a0;
        a1 = (a1 > 0.f) ? a1 : NEG_SLOPE * a1;
        a2 = (a2 > 0.f) ? a2 : NEG_SLOPE * a2;
        a3 = (a3 > 0.f) ? a3 : NEG_SLOPE * a3;
        float w0 = __expf(a0);
        float w1 = __expf(a1);
        float w2 = __expf(a2);
        float w3 = __expf(a3);
        float2 f0 = __half22float2(x0);
        float2 f1 = __half22float2(x1);
        float2 f2 = __half22float2(x2);
        float2 f3 = __half22float2(x3);
        ax = fmaf(w0, f0.x, fmaf(w1, f1.x, fmaf(w2, f2.x, fmaf(w3, f3.x, ax))));
        ay = fmaf(w0, f0.y, fmaf(w1, f1.y, fmaf(w2, f2.y, fmaf(w3, f3.y, ay))));
        sw += (w0 + w1) + (w2 + w3);
    }
    for (; i < end; ++i) {
        int s0 = eidx[i];
        __half2 x0 = *(const __half2*)(xh + ((uint)s0 * OUT_ + choff));
        float a0 = asrc[(uint)s0 * H_ + h] + adst_h;
        a0 = (a0 > 0.f) ? a0 : NEG_SLOPE * a0;
        float w0 = __expf(a0);
        float2 f0 = __half22float2(x0);
        ax = fmaf(w0, f0.x, ax);
        ay = fmaf(w0, f0.y, ay);
        sw += w0;
    }
    // self-loop
    {
        float al = asrc[(uint)dn * H_ + h] + adst_h;
        al = (al > 0.f) ? al : NEG_SLOPE * al;
        float w = __expf(al);
        __half2 xv = *(const __half2*)(xh + ((uint)dn * OUT_ + choff));
        float2 fv = __half22float2(xv);
        ax = fmaf(w, fv.x, ax);
        ay = fmaf(w, fv.y, ay);
        sw += w;
    }
    float ox = ax / sw + bias[lane * 2];
    float oy = ay / sw + bias[lane * 2 + 1];
    ox = (ox > 0.f) ? ox : expm1f(ox);
    oy = (oy > 0.f) ? oy : expm1f(oy);
    *(float2*)&emb[(size_t)dn * OUT_ + lane * 2] = make_float2(ox, oy);
    *(__half2*)&embh[(size_t)dn * OUT_ + lane * 2] = __floats2half2_rn(ox, oy);
}

// K5: mean-pool numerator. 32 nodes/block; run-length accumulate (batch sorted).
__global__ void k_pool(const float* __restrict__ emb, const int* __restrict__ batch,
                       float* __restrict__ gsum) {
    int j = threadIdx.x & 127;
    int half = threadIdx.x >> 7;
    int base = blockIdx.x * 32 + half * 16;
    float run = 0.f;
    int gcur = -1;
    for (int i = 0; i < 16; ++i) {
        int n = base + i;
        if (n >= N_) break;
        int g = batch[n];
        if (g != gcur) {
            if (gcur >= 0) unsafeAtomicAdd(&gsum[gcur * OUT_ + j], run);
            gcur = g; run = 0.f;
        }
        run += emb[(size_t)n * OUT_ + j];
    }
    if (gcur >= 0) unsafeAtomicAdd(&gsum[gcur * OUT_ + j], run);
}

// K6: fused per-graph: count (binary search), gemb = gsum/cnt -> output,
// gpart = gemb @ W1b + b1. One block per graph, 128 threads.
__global__ void k_graph(const int* __restrict__ batch, const float* __restrict__ gsum,
                        const float* __restrict__ W1, const float* __restrict__ b1,
                        float* __restrict__ outg, float* __restrict__ gpart) {
    const int g = blockIdx.x;
    const int j = threadIdx.x;   // 128
    __shared__ float ge[128];
    __shared__ int cnt_s;
    if (j == 0) {
        int lo = 0, hi = N_;
        while (lo < hi) { int m = (lo + hi) >> 1; if (batch[m] < g) lo = m + 1; else hi = m; }
        int start = lo;
        lo = 0; hi = N_;
        while (lo < hi) { int m = (lo + hi) >> 1; if (batch[m] <= g) lo = m + 1; else hi = m; }
        cnt_s = lo - start;
    }
    __syncthreads();
    float v = gsum[g * 128 + j] / fmaxf((float)cnt_s, 1.f);
    ge[j] = v;
    outg[g * 128 + j] = v;
    __syncthreads();
    float s = b1[j];
    const float* w = W1 + (size_t)128 * 128 + j;
    for (int k = 0; k < 128; ++k) s = fmaf(ge[k], w[(size_t)k * 128], s);
    gpart[g * 128 + j] = s;
}

// K7: MFMA decoder. 64 nodes/block, 4 waves; wave w owns M-tile w (16 nodes).
// h = relu(embh@Wt^T + gpart[batch]); scores = h@W2 + b2.
__global__ __launch_bounds__(256) void k_dec3(const __half* __restrict__ embh,
                                              const __half* __restrict__ wtg,
                                              const float* __restrict__ gpart,
                                              const int* __restrict__ batch,
                                              const float* __restrict__ W2,
                                              const float* __restrict__ b2,
                                              float* __restrict__ scores) {
    __shared__ _Float16 wt_s[128][128];    // 32 KB: Wt[j][k]
    __shared__ _Float16 emb_s[64][128];    // 16 KB: A[node][k]
    __shared__ float    w2_s[128];
    const int base = blockIdx.x * 64;
    const int tid  = threadIdx.x;

    // load Wt (2048 16B-chunks), emb tile (1024 chunks), W2
    for (int c = tid; c < 2048; c += 256) {
        int j = c >> 4, kk = (c & 15) * 8;
        *(float4*)&wt_s[j][kk] = *(const float4*)&wtg[j * 128 + kk];
    }
    for (int c = tid; c < 1024; c += 256) {
        int nl = c >> 4, kk = (c & 15) * 8;
        int n = base + nl;
        if (n < N_)
            *(float4*)&emb_s[nl][kk] = *(const float4*)&embh[(size_t)n * 128 + kk];
        else
            *(float4*)&emb_s[nl][kk] = make_float4(0.f, 0.f, 0.f, 0.f);
    }
    if (tid < 128) w2_s[tid] = W2[tid];
    __syncthreads();

    const int wv   = tid >> 6;          // M-tile (0..3)
    const int lane = tid & 63;
    const int rc   = lane & 15;         // row for A / col for B,D
    const int kh   = lane >> 4;         // k-half index (0..3)

    f32x4 acc[8];
#pragma unroll
    for (int nt = 0; nt < 8; ++nt) acc[nt] = (f32x4){0.f, 0.f, 0.f, 0.f};

#pragma unroll
    for (int kt = 0; kt < 4; ++kt) {
        f16x8 a = *(const f16x8*)&emb_s[wv * 16 + rc][kt * 32 + kh * 8];
#pragma unroll
        for (int nt = 0; nt < 8; ++nt) {
            f16x8 b = *(const f16x8*)&wt_s[nt * 16 + rc][kt * 32 + kh * 8];
            acc[nt] = __builtin_amdgcn_mfma_f32_16x16x32_f16(a, b, acc[nt], 0, 0, 0);
        }
    }

    // epilogue: D[row=(kh*4+r)][col=rc] per tile; node = base + wv*16 + kh*4 + r
    const float b2v = b2[0];
    float s[4] = {0.f, 0.f, 0.f, 0.f};
    int   gi[4];
#pragma unroll
    for (int r = 0; r < 4; ++r) {
        int n = base + wv * 16 + kh * 4 + r;
        gi[r] = (n < N_) ? batch[n] : 0;
    }
#pragma unroll
    for (int nt = 0; nt < 8; ++nt) {
        int j = nt * 16 + rc;
        float w2 = w2_s[j];
#pragma unroll
        for (int r = 0; r < 4; ++r) {
            float hv = acc[nt][r] + gpart[(size_t)gi[r] * 128 + j];
            hv = (hv > 0.f) ? hv : 0.f;
            s[r] = fmaf(hv, w2, s[r]);
        }
    }
#pragma unroll
    for (int r = 0; r < 4; ++r) {
#pragma unroll
        for (int m = 8; m >= 1; m >>= 1) s[r] += __shfl_xor(s[r], m, 16);
    }
    if (rc == 0) {
#pragma unroll
        for (int r = 0; r < 4; ++r) {
            int n = base + wv * 16 + kh * 4 + r;
            if (n < N_) scores[n] = s[r] + b2v;
        }
    }
}

extern "C" void kernel_launch(void* const* d_in, const int* in_sizes, int n_in,
                              void* d_out, int out_size, void* d_ws, size_t ws_size,
                              hipStream_t stream) {
    const float* feat   = (const float*)d_in[0];
    const int*   ei     = (const int*)d_in[1];
    const int*   batch  = (const int*)d_in[2];
    const float* Wg     = (const float*)d_in[3];
    const float* att_s  = (const float*)d_in[4];
    const float* att_d  = (const float*)d_in[5];
    const float* bias_g = (const float*)d_in[6];
    const float* W1     = (const float*)d_in[7];
    const float* b1     = (const float*)d_in[8];
    const float* W2     = (const float*)d_in[9];
    const float* b2     = (const float*)d_in[10];
    char*  wsb = (char*)d_ws;
    float* out = (float*)d_out;

    const int* src = ei;        // edge_index[0]
    const int* dst = ei + E_;   // edge_index[1]

    __half* XH   = (__half*)(wsb + OFF_X);
    __half* EMBH = (__half*)(wsb + OFF_EMBH);
    float* ASRC  = (float*)(wsb + OFF_ASRC);
    float* ADST  = (float*)(wsb + OFF_ADST);
    float* EMB   = (float*)(wsb + OFF_EMB);
    float* GSUM  = (float*)(wsb + OFF_GSUM);
    int*   DEG   = (int*)  (wsb + OFF_DEG);
    __half* WT   = (__half*)(wsb + OFF_WT);
    int*   ROWS  = (int*)  (wsb + OFF_ROWS);
    int*   CUR   = (int*)  (wsb + OFF_CUR);
    int*   EIDX  = (int*)  (wsb + OFF_EIDX);
    int*   BSUM  = (int*)  (wsb + OFF_BSUM);
    int*   BOFF  = (int*)  (wsb + OFF_BOFF);
    float* GPART = (float*)(wsb + OFF_GPART);

    hipMemsetAsync(wsb + ZERO_BEG, 0, ZERO_LEN, stream);

    k_transform<<<N_ / 16, 256, 0, stream>>>(feat, Wg, att_s, att_d, XH, ASRC, ADST);
    k_w1t<<<128, 128, 0, stream>>>(W1, WT);
    k_hist<<<(E_ + 255) / 256, 256, 0, stream>>>(dst, DEG);
    k_blocksum<<<NB_, 256, 0, stream>>>(DEG, BSUM);
    k_scanb<<<1, 256, 0, stream>>>(BSUM, BOFF);
    k_scanfin<<<NB_, 256, 0, stream>>>(DEG, BOFF, ROWS, CUR);
    k_scatter<<<(E_ + 255) / 256, 256, 0, stream>>>(src, dst, CUR, EIDX);
    k_agg<<<N_ / 4, 256, 0, stream>>>(ROWS, EIDX, XH, ASRC, ADST, bias_g, EMB, EMBH);
    k_pool<<<(N_ + 31) / 32, 256, 0, stream>>>(EMB, batch, GSUM);
    k_graph<<<G_, 128, 0, stream>>>(batch, GSUM, W1, b1, out + N_, GPART);
    k_dec3<<<(N_ + 63) / 64, 256, 0, stream>>>(EMBH, WT, GPART, batch, W2, b2, out);
}

// Round 9
// 197.018 us; speedup vs baseline: 1.3007x; 1.0886x over previous
//
#include <hip/hip_runtime.h>
#include <hip/hip_bf16.h>
#include <hip/hip_fp16.h>

constexpr int N_   = 50000;
constexpr int E_   = 800000;
constexpr int G_   = 256;
constexpr int IN_  = 64;
constexpr int H_   = 8;
constexpr int OUT_ = 128;   // H*C
constexpr float NEG_SLOPE = 0.2f;
constexpr int NB_    = (N_ + 255) / 256;   // 196 scan blocks
constexpr int NBUCK  = (N_ + 255) / 256;   // 196 dst-buckets (dst>>8)
constexpr int EPB    = 4096;               // edges per bin block

typedef _Float16 f16x8 __attribute__((ext_vector_type(8)));
typedef float    f32x4 __attribute__((ext_vector_type(4)));

// ---- workspace layout (byte offsets, all 256B-aligned) ----
constexpr size_t OFF_X      = 0;                                  // [N,128] f16 xh
constexpr size_t OFF_EMBH   = OFF_X     + (size_t)N_*OUT_*2;      // [N,128] f16 emb
constexpr size_t OFF_ASRC   = OFF_X     + (size_t)N_*OUT_*4;      // [N,8]  f32
constexpr size_t OFF_ADST   = OFF_ASRC  + (size_t)N_*H_*4;        // [N,8]  f32
constexpr size_t OFF_PAIRS  = OFF_ADST  + (size_t)N_*H_*4;        // [E] u32 packed (old EMB slot)
constexpr size_t OFF_GSUM   = OFF_PAIRS + (size_t)N_*OUT_*4;      // [G,128] f32 (zeroed)
constexpr size_t OFF_DEG    = OFF_GSUM  + (size_t)G_*OUT_*4;      // [N] int (zeroed)
constexpr size_t OFF_WT     = OFF_DEG   + (size_t)N_*4;           // [128,128] f16 W1a^T
constexpr size_t OFF_BSTART = OFF_WT    + (size_t)G_*OUT_*4;      // [NBUCK+1] int
constexpr size_t OFF_GCUR   = OFF_BSTART+ 1024;                   // [NBUCK] int
constexpr size_t OFF_ROWS   = OFF_GCUR  + 1024;                   // [N+1] int
constexpr size_t OFF_CUR    = OFF_ROWS  + (size_t)(N_+1)*4 + 252; // [N] int
constexpr size_t OFF_EIDX   = OFF_CUR   + (size_t)N_*4;           // [E] int (src per slot)
constexpr size_t OFF_BSUM   = OFF_EIDX  + (size_t)E_*4;           // [NB] int
constexpr size_t OFF_BOFF   = OFF_BSUM  + (size_t)NB_*4 + 240;    // [NB] int
constexpr size_t OFF_GPART  = OFF_BOFF  + (size_t)NB_*4 + 240;    // [G,128] f32
constexpr size_t ZERO_BEG   = OFF_GSUM;
constexpr size_t ZERO_LEN   = OFF_WT - OFF_GSUM;                  // gsum + deg

// K1: x = feat @ W_gat (f16 out); a_src/a_dst per-head dots. 16 nodes/block.
__global__ void k_transform(const float* __restrict__ feat, const float* __restrict__ Wg,
                            const float* __restrict__ att_s, const float* __restrict__ att_d,
                            __half* __restrict__ xh, float* __restrict__ asrc,
                            float* __restrict__ adst) {
    const int base = blockIdx.x * 16;
    const int j    = threadIdx.x & 127;
    const int half = threadIdx.x >> 7;

    __shared__ float f[16][IN_];
    for (int t = threadIdx.x; t < 16 * IN_; t += 256) {
        int ni = t >> 6, k = t & 63;
        f[ni][k] = feat[(size_t)(base + ni) * IN_ + k];
    }
    __syncthreads();

    float acc[8];
#pragma unroll
    for (int i = 0; i < 8; ++i) acc[i] = 0.f;
    for (int k = 0; k < IN_; ++k) {
        float w = Wg[k * OUT_ + j];
#pragma unroll
        for (int i = 0; i < 8; ++i) acc[i] += f[half * 8 + i][k] * w;
    }
    const float aw_s = att_s[j];
    const float aw_d = att_d[j];
#pragma unroll
    for (int i = 0; i < 8; ++i) {
        int n = base + half * 8 + i;
        xh[(size_t)n * OUT_ + j] = __float2half(acc[i]);
        float ps = acc[i] * aw_s;
        float pd = acc[i] * aw_d;
#pragma unroll
        for (int m = 8; m >= 1; m >>= 1) {
            ps += __shfl_xor(ps, m, 16);
            pd += __shfl_xor(pd, m, 16);
        }
        if ((j & 15) == 0) {
            asrc[n * H_ + (j >> 4)] = ps;
            adst[n * H_ + (j >> 4)] = pd;
        }
    }
}

// K1b: Wt[j][k] = f16(W1[k][j]) for k<128 (W1a transpose).
__global__ void k_w1t(const float* __restrict__ W1, __half* __restrict__ wt) {
    const int j = blockIdx.x;     // 128
    const int k = threadIdx.x;    // 128
    wt[j * 128 + k] = __float2half(W1[(size_t)k * 128 + j]);
}

// K2a: in-degree histogram.
__global__ void k_hist(const int* __restrict__ dst, int* __restrict__ deg) {
    int e = blockIdx.x * 256 + threadIdx.x;
    if (e < E_) atomicAdd(&deg[dst[e]], 1);
}

// K2b-1: per-block sums of deg.
__global__ void k_blocksum(const int* __restrict__ deg, int* __restrict__ bsum) {
    int i = blockIdx.x * 256 + threadIdx.x;
    int v = (i < N_) ? deg[i] : 0;
#pragma unroll
    for (int m = 32; m >= 1; m >>= 1) v += __shfl_xor(v, m, 64);
    __shared__ int ws[4];
    if ((threadIdx.x & 63) == 0) ws[threadIdx.x >> 6] = v;
    __syncthreads();
    if (threadIdx.x == 0) bsum[blockIdx.x] = ws[0] + ws[1] + ws[2] + ws[3];
}

// K2b-2: exclusive scan of the NB block sums (one block).
__global__ void k_scanb(const int* __restrict__ bsum, int* __restrict__ boff) {
    __shared__ int s[256];
    int t = threadIdx.x;
    int v = (t < NB_) ? bsum[t] : 0;
    s[t] = v;
    __syncthreads();
    for (int off = 1; off < 256; off <<= 1) {
        int u = (t >= off) ? s[t - off] : 0;
        __syncthreads();
        s[t] += u;
        __syncthreads();
    }
    if (t < NB_) boff[t] = s[t] - v;   // exclusive
}

// K2b-3: block-local exclusive scan + block offset -> rowstart, cursor.
__global__ void k_scanfin(const int* __restrict__ deg, const int* __restrict__ boff,
                          int* __restrict__ rowstart, int* __restrict__ cursor) {
    __shared__ int s[256];
    int t = threadIdx.x;
    int i = blockIdx.x * 256 + t;
    int v = (i < N_) ? deg[i] : 0;
    s[t] = v;
    __syncthreads();
    for (int off = 1; off < 256; off <<= 1) {
        int u = (t >= off) ? s[t - off] : 0;
        __syncthreads();
        s[t] += u;
        __syncthreads();
    }
    if (i < N_) {
        int r = boff[blockIdx.x] + s[t] - v;
        rowstart[i] = r;
        cursor[i]   = r;
    }
    if (i == N_ - 1) rowstart[N_] = E_;
}

// K2c-0: bucket bases from rowstart (bstart immutable, gcur mutable).
__global__ void k_binit(const int* __restrict__ rowstart, int* __restrict__ bstart,
                        int* __restrict__ gcur) {
    int b = threadIdx.x;
    if (b <= NBUCK) {
        int v = rowstart[min(b * 256, N_)];
        bstart[b] = v;
        if (b < NBUCK) gcur[b] = v;
    }
}

// K2c-1: bin edges by dst>>8 into per-bucket contiguous runs (packed rel|src).
__global__ __launch_bounds__(256) void k_bin(const int* __restrict__ src,
                                             const int* __restrict__ dst,
                                             int* __restrict__ gcur,
                                             unsigned int* __restrict__ pairs) {
    __shared__ int cnt[NBUCK];
    __shared__ int base[NBUCK];
    const int tid = threadIdx.x;
    for (int i = tid; i < NBUCK; i += 256) cnt[i] = 0;
    __syncthreads();
    const int e0 = blockIdx.x * EPB;
    const int ne = min(EPB, E_ - e0);
    for (int i = tid; i < ne; i += 256) atomicAdd(&cnt[dst[e0 + i] >> 8], 1);
    __syncthreads();
    for (int i = tid; i < NBUCK; i += 256) {
        int c = cnt[i];
        base[i] = (c > 0) ? atomicAdd(&gcur[i], c) : 0;
        cnt[i] = 0;   // reuse as local cursor
    }
    __syncthreads();
    for (int i = tid; i < ne; i += 256) {
        int d = dst[e0 + i];
        int s = src[e0 + i];
        int b = d >> 8;
        int p = base[b] + atomicAdd(&cnt[b], 1);
        pairs[p] = ((unsigned int)(d & 255) << 16) | (unsigned int)s;
    }
}

// K2c-2: per-bucket scatter into final CSR slots (writes confined to ~16KB window).
__global__ __launch_bounds__(256) void k_scat2(const unsigned int* __restrict__ pairs,
                                               const int* __restrict__ bstart,
                                               int* __restrict__ cursor,
                                               int* __restrict__ eidx) {
    const int b   = blockIdx.x;
    const int beg = bstart[b];
    const int end = bstart[b + 1];
    const int dbase = b << 8;
    for (int i = beg + threadIdx.x; i < end; i += 256) {
        unsigned int pk = pairs[i];
        int d = dbase + (int)(pk >> 16);
        int s = (int)(pk & 0xFFFFu);
        int pos = atomicAdd(&cursor[d], 1);
        eidx[pos] = s;
    }
}

// K3: CSR aggregation (4-edge unroll; gathers independent of exp chain).
__global__ void k_agg(const int* __restrict__ rowstart, const int* __restrict__ eidx,
                      const __half* __restrict__ xh, const float* __restrict__ asrc,
                      const float* __restrict__ adst, const float* __restrict__ bias,
                      __half* __restrict__ embh) {
    const int dn   = blockIdx.x * 4 + (threadIdx.x >> 6);   // wave-uniform
    const int lane = threadIdx.x & 63;
    const int h    = lane >> 3;
    const float adst_h = adst[dn * H_ + h];
    const uint choff = (uint)lane * 2;

    const int beg = rowstart[dn];
    const int end = rowstart[dn + 1];

    float ax = 0.f, ay = 0.f, sw = 0.f;
    int i = beg;
    for (; i + 3 < end; i += 4) {
        int s0 = eidx[i];
        int s1 = eidx[i + 1];
        int s2 = eidx[i + 2];
        int s3 = eidx[i + 3];
        __half2 x0 = *(const __half2*)(xh + ((uint)s0 * OUT_ + choff));
        __half2 x1 = *(const __half2*)(xh + ((uint)s1 * OUT_ + choff));
        __half2 x2 = *(const __half2*)(xh + ((uint)s2 * OUT_ + choff));
        __half2 x3 = *(const __half2*)(xh + ((uint)s3 * OUT_ + choff));
        float a0 = asrc[(uint)s0 * H_ + h] + adst_h;
        float a1 = asrc[(uint)s1 * H_ + h] + adst_h;
        float a2 = asrc[(uint)s2 * H_ + h] + adst_h;
        float a3 = asrc[(uint)s3 * H_ + h] + adst_h;
        a0 = (a0 > 0.f) ? a0 : NEG_SLOPE * a0;
        a1 = (a1 > 0.f) ? a1 : NEG_SLOPE * a1;
        a2 = (a2 > 0.f) ? a2 : NEG_SLOPE * a2;
        a3 = (a3 > 0.f) ? a3 : NEG_SLOPE * a3;
        float w0 = __expf(a0);
        float w1 = __expf(a1);
        float w2 = __expf(a2);
        float w3 = __expf(a3);
        float2 f0 = __half22float2(x0);
        float2 f1 = __half22float2(x1);
        float2 f2 = __half22float2(x2);
        float2 f3 = __half22float2(x3);
        ax = fmaf(w0, f0.x, fmaf(w1, f1.x, fmaf(w2, f2.x, fmaf(w3, f3.x, ax))));
        ay = fmaf(w0, f0.y, fmaf(w1, f1.y, fmaf(w2, f2.y, fmaf(w3, f3.y, ay))));
        sw += (w0 + w1) + (w2 + w3);
    }
    for (; i < end; ++i) {
        int s0 = eidx[i];
        __half2 x0 = *(const __half2*)(xh + ((uint)s0 * OUT_ + choff));
        float a0 = asrc[(uint)s0 * H_ + h] + adst_h;
        a0 = (a0 > 0.f) ? a0 : NEG_SLOPE * a0;
        float w0 = __expf(a0);
        float2 f0 = __half22float2(x0);
        ax = fmaf(w0, f0.x, ax);
        ay = fmaf(w0, f0.y, ay);
        sw += w0;
    }
    // self-loop
    {
        float al = asrc[(uint)dn * H_ + h] + adst_h;
        al = (al > 0.f) ? al : NEG_SLOPE * al;
        float w = __expf(al);
        __half2 xv = *(const __half2*)(xh + ((uint)dn * OUT_ + choff));
        float2 fv = __half22float2(xv);
        ax = fmaf(w, fv.x, ax);
        ay = fmaf(w, fv.y, ay);
        sw += w;
    }
    float ox = ax / sw + bias[lane * 2];
    float oy = ay / sw + bias[lane * 2 + 1];
    ox = (ox > 0.f) ? ox : expm1f(ox);
    oy = (oy > 0.f) ? oy : expm1f(oy);
    *(__half2*)&embh[(size_t)dn * OUT_ + lane * 2] = __floats2half2_rn(ox, oy);
}

// K5: mean-pool numerator from f16 emb. 64 nodes/block, 16-node runs.
__global__ void k_pool(const __half* __restrict__ embh, const int* __restrict__ batch,
                       float* __restrict__ gsum) {
    int c   = threadIdx.x & 63;    // half2 channel pair (2c, 2c+1)
    int grp = threadIdx.x >> 6;    // 0..3
    int base = blockIdx.x * 64 + grp * 16;
    float rx = 0.f, ry = 0.f;
    int gcur = -1;
    for (int i = 0; i < 16; ++i) {
        int n = base + i;
        if (n >= N_) break;
        int g = batch[n];
        if (g != gcur) {
            if (gcur >= 0) {
                unsafeAtomicAdd(&gsum[gcur * OUT_ + 2 * c], rx);
                unsafeAtomicAdd(&gsum[gcur * OUT_ + 2 * c + 1], ry);
            }
            gcur = g; rx = ry = 0.f;
        }
        __half2 v = *(const __half2*)&embh[(size_t)n * OUT_ + 2 * c];
        float2 f = __half22float2(v);
        rx += f.x; ry += f.y;
    }
    if (gcur >= 0) {
        unsafeAtomicAdd(&gsum[gcur * OUT_ + 2 * c], rx);
        unsafeAtomicAdd(&gsum[gcur * OUT_ + 2 * c + 1], ry);
    }
}

// K6: fused per-graph: count, gemb -> output, gpart = gemb @ W1b + b1.
__global__ void k_graph(const int* __restrict__ batch, const float* __restrict__ gsum,
                        const float* __restrict__ W1, const float* __restrict__ b1,
                        float* __restrict__ outg, float* __restrict__ gpart) {
    const int g = blockIdx.x;
    const int j = threadIdx.x;   // 128
    __shared__ float ge[128];
    __shared__ int cnt_s;
    if (j == 0) {
        int lo = 0, hi = N_;
        while (lo < hi) { int m = (lo + hi) >> 1; if (batch[m] < g) lo = m + 1; else hi = m; }
        int start = lo;
        lo = 0; hi = N_;
        while (lo < hi) { int m = (lo + hi) >> 1; if (batch[m] <= g) lo = m + 1; else hi = m; }
        cnt_s = lo - start;
    }
    __syncthreads();
    float v = gsum[g * 128 + j] / fmaxf((float)cnt_s, 1.f);
    ge[j] = v;
    outg[g * 128 + j] = v;
    __syncthreads();
    float s = b1[j];
    const float* w = W1 + (size_t)128 * 128 + j;
    for (int k = 0; k < 128; ++k) s = fmaf(ge[k], w[(size_t)k * 128], s);
    gpart[g * 128 + j] = s;
}

// K7: MFMA decoder. 64 nodes/block, 4 waves.
__global__ __launch_bounds__(256) void k_dec3(const __half* __restrict__ embh,
                                              const __half* __restrict__ wtg,
                                              const float* __restrict__ gpart,
                                              const int* __restrict__ batch,
                                              const float* __restrict__ W2,
                                              const float* __restrict__ b2,
                                              float* __restrict__ scores) {
    __shared__ _Float16 wt_s[128][128];    // 32 KB
    __shared__ _Float16 emb_s[64][128];    // 16 KB
    __shared__ float    w2_s[128];
    const int base = blockIdx.x * 64;
    const int tid  = threadIdx.x;

    for (int c = tid; c < 2048; c += 256) {
        int j = c >> 4, kk = (c & 15) * 8;
        *(float4*)&wt_s[j][kk] = *(const float4*)&wtg[j * 128 + kk];
    }
    for (int c = tid; c < 1024; c += 256) {
        int nl = c >> 4, kk = (c & 15) * 8;
        int n = base + nl;
        if (n < N_)
            *(float4*)&emb_s[nl][kk] = *(const float4*)&embh[(size_t)n * 128 + kk];
        else
            *(float4*)&emb_s[nl][kk] = make_float4(0.f, 0.f, 0.f, 0.f);
    }
    if (tid < 128) w2_s[tid] = W2[tid];
    __syncthreads();

    const int wv   = tid >> 6;
    const int lane = tid & 63;
    const int rc   = lane & 15;
    const int kh   = lane >> 4;

    f32x4 acc[8];
#pragma unroll
    for (int nt = 0; nt < 8; ++nt) acc[nt] = (f32x4){0.f, 0.f, 0.f, 0.f};

#pragma unroll
    for (int kt = 0; kt < 4; ++kt) {
        f16x8 a = *(const f16x8*)&emb_s[wv * 16 + rc][kt * 32 + kh * 8];
#pragma unroll
        for (int nt = 0; nt < 8; ++nt) {
            f16x8 b = *(const f16x8*)&wt_s[nt * 16 + rc][kt * 32 + kh * 8];
            acc[nt] = __builtin_amdgcn_mfma_f32_16x16x32_f16(a, b, acc[nt], 0, 0, 0);
        }
    }

    const float b2v = b2[0];
    float s[4] = {0.f, 0.f, 0.f, 0.f};
    int   gi[4];
#pragma unroll
    for (int r = 0; r < 4; ++r) {
        int n = base + wv * 16 + kh * 4 + r;
        gi[r] = (n < N_) ? batch[n] : 0;
    }
#pragma unroll
    for (int nt = 0; nt < 8; ++nt) {
        int j = nt * 16 + rc;
        float w2 = w2_s[j];
#pragma unroll
        for (int r = 0; r < 4; ++r) {
            float hv = acc[nt][r] + gpart[(size_t)gi[r] * 128 + j];
            hv = (hv > 0.f) ? hv : 0.f;
            s[r] = fmaf(hv, w2, s[r]);
        }
    }
#pragma unroll
    for (int r = 0; r < 4; ++r) {
#pragma unroll
        for (int m = 8; m >= 1; m >>= 1) s[r] += __shfl_xor(s[r], m, 16);
    }
    if (rc == 0) {
#pragma unroll
        for (int r = 0; r < 4; ++r) {
            int n = base + wv * 16 + kh * 4 + r;
            if (n < N_) scores[n] = s[r] + b2v;
        }
    }
}

extern "C" void kernel_launch(void* const* d_in, const int* in_sizes, int n_in,
                              void* d_out, int out_size, void* d_ws, size_t ws_size,
                              hipStream_t stream) {
    const float* feat   = (const float*)d_in[0];
    const int*   ei     = (const int*)d_in[1];
    const int*   batch  = (const int*)d_in[2];
    const float* Wg     = (const float*)d_in[3];
    const float* att_s  = (const float*)d_in[4];
    const float* att_d  = (const float*)d_in[5];
    const float* bias_g = (const float*)d_in[6];
    const float* W1     = (const float*)d_in[7];
    const float* b1     = (const float*)d_in[8];
    const float* W2     = (const float*)d_in[9];
    const float* b2     = (const float*)d_in[10];
    char*  wsb = (char*)d_ws;
    float* out = (float*)d_out;

    const int* src = ei;        // edge_index[0]
    const int* dst = ei + E_;   // edge_index[1]

    __half* XH    = (__half*)(wsb + OFF_X);
    __half* EMBH  = (__half*)(wsb + OFF_EMBH);
    float*  ASRC  = (float*)(wsb + OFF_ASRC);
    float*  ADST  = (float*)(wsb + OFF_ADST);
    unsigned int* PAIRS = (unsigned int*)(wsb + OFF_PAIRS);
    float*  GSUM  = (float*)(wsb + OFF_GSUM);
    int*    DEG   = (int*)  (wsb + OFF_DEG);
    __half* WT    = (__half*)(wsb + OFF_WT);
    int*    BSTART= (int*)  (wsb + OFF_BSTART);
    int*    GCUR  = (int*)  (wsb + OFF_GCUR);
    int*    ROWS  = (int*)  (wsb + OFF_ROWS);
    int*    CUR   = (int*)  (wsb + OFF_CUR);
    int*    EIDX  = (int*)  (wsb + OFF_EIDX);
    int*    BSUM  = (int*)  (wsb + OFF_BSUM);
    int*    BOFF  = (int*)  (wsb + OFF_BOFF);
    float*  GPART = (float*)(wsb + OFF_GPART);

    hipMemsetAsync(wsb + ZERO_BEG, 0, ZERO_LEN, stream);

    k_transform<<<N_ / 16, 256, 0, stream>>>(feat, Wg, att_s, att_d, XH, ASRC, ADST);
    k_w1t<<<128, 128, 0, stream>>>(W1, WT);
    k_hist<<<(E_ + 255) / 256, 256, 0, stream>>>(dst, DEG);
    k_blocksum<<<NB_, 256, 0, stream>>>(DEG, BSUM);
    k_scanb<<<1, 256, 0, stream>>>(BSUM, BOFF);
    k_scanfin<<<NB_, 256, 0, stream>>>(DEG, BOFF, ROWS, CUR);
    k_binit<<<1, 256, 0, stream>>>(ROWS, BSTART, GCUR);
    k_bin<<<(E_ + EPB - 1) / EPB, 256, 0, stream>>>(src, dst, GCUR, PAIRS);
    k_scat2<<<NBUCK, 256, 0, stream>>>(PAIRS, BSTART, CUR, EIDX);
    k_agg<<<N_ / 4, 256, 0, stream>>>(ROWS, EIDX, XH, ASRC, ADST, bias_g, EMBH);
    k_pool<<<(N_ + 63) / 64, 256, 0, stream>>>(EMBH, batch, GSUM);
    k_graph<<<G_, 128, 0, stream>>>(batch, GSUM, W1, b1, out + N_, GPART);
    k_dec3<<<(N_ + 63) / 64, 256, 0, stream>>>(EMBH, WT, GPART, batch, W2, b2, out);
}

// Round 10
// 134.425 us; speedup vs baseline: 1.9064x; 1.4656x over previous
//
#include <hip/hip_runtime.h>
#include <hip/hip_bf16.h>
#include <hip/hip_fp16.h>

constexpr int N_   = 50000;
constexpr int E_   = 800000;
constexpr int G_   = 256;
constexpr int IN_  = 64;
constexpr int H_   = 8;
constexpr int OUT_ = 128;   // H*C
constexpr float NEG_SLOPE = 0.2f;
constexpr int NBUCK = (N_ + 255) / 256;   // 196 dst-buckets (dst>>8)
constexpr int EPB   = 4096;               // edges per bin block
constexpr int CAP   = 6144;               // bucket capacity (mean 4096, sd 64)

typedef _Float16 f16x8 __attribute__((ext_vector_type(8)));
typedef float    f32x4 __attribute__((ext_vector_type(4)));

// ---- workspace layout (byte offsets, 256B-aligned) ----
constexpr size_t OFF_X      = 0;                                   // [N,128] f16 xh
constexpr size_t OFF_EMBH   = OFF_X      + (size_t)N_*OUT_*2;      // [N,128] f16 emb
constexpr size_t OFF_ASRC   = OFF_X      + (size_t)N_*OUT_*4;      // [N,8] f32
constexpr size_t OFF_ADST   = OFF_ASRC   + (size_t)N_*H_*4;        // [N,8] f32
constexpr size_t OFF_PAIRS  = OFF_ADST   + (size_t)N_*H_*4;        // [NBUCK*CAP] u32
constexpr size_t OFF_GSUM   = OFF_PAIRS  + (size_t)NBUCK*CAP*4;    // [G,128] f32 (zeroed)
constexpr size_t OFF_BCNT   = OFF_GSUM   + (size_t)G_*OUT_*4;      // [NBUCK] int (zeroed)
constexpr size_t OFF_WT     = OFF_BCNT   + 1024;                   // [128,128] f16 W1a^T
constexpr size_t OFF_WP     = OFF_WT     + 128*128*2;              // [144,64] f16 Wp[j][k]
constexpr size_t OFF_BSTART = OFF_WP     + 18432;                  // [NBUCK+1] int
constexpr size_t OFF_ROWS   = OFF_BSTART + 1024;                   // [N+1] int
constexpr size_t OFF_EIDX   = OFF_ROWS   + 200448;                 // [E] int
constexpr size_t OFF_GPART  = OFF_EIDX   + (size_t)E_*4;           // [G,128] f32
constexpr size_t ZERO_BEG   = OFF_GSUM;
constexpr size_t ZERO_LEN   = OFF_WT - OFF_GSUM;                   // gsum + bcnt

// K0: prep weights. Blocks: 0 -> Wp att cols; 1..8 -> Wp main; 9..16 -> WT.
__global__ void k_prep(const float* __restrict__ Wg, const float* __restrict__ att_s,
                       const float* __restrict__ att_d, const float* __restrict__ W1,
                       __half* __restrict__ wp, __half* __restrict__ wt) {
    const int b = blockIdx.x, t = threadIdx.x;
    if (b == 0) {
        // Wp[128+j'][k], j'=0..15: head h=j'&7, src half j'<8 else dst
        for (int idx = t; idx < 16 * 64; idx += 256) {
            int jp = idx >> 6, k = idx & 63;
            int h = jp & 7;
            const float* att = (jp < 8) ? att_s : att_d;
            float s = 0.f;
#pragma unroll
            for (int c = 0; c < 16; ++c)
                s = fmaf(Wg[k * 128 + h * 16 + c], att[h * 16 + c], s);
            wp[(128 + jp) * 64 + k] = __float2half(s);
        }
    } else if (b <= 8) {
        for (int idx = t; idx < 1024; idx += 256) {
            int e = (b - 1) * 1024 + idx;
            int j = e >> 6, k = e & 63;
            wp[j * 64 + k] = __float2half(Wg[k * 128 + j]);
        }
    } else {
        for (int idx = t; idx < 2048; idx += 256) {
            int e = (b - 9) * 2048 + idx;
            int j = e >> 7, k = e & 127;
            wt[j * 128 + k] = __float2half(W1[(size_t)k * 128 + j]);
        }
    }
}

// K1: MFMA transform: [64 nodes] x Wp[144,64] -> xh (j<128), asrc/adst (j>=128).
__global__ __launch_bounds__(256) void k_xform(const float* __restrict__ feat,
                                               const __half* __restrict__ wp,
                                               __half* __restrict__ xh,
                                               float* __restrict__ asrc,
                                               float* __restrict__ adst) {
    __shared__ _Float16 fs[64][64];      // 8 KB
    __shared__ _Float16 wp_s[144][64];   // 18 KB
    const int base = blockIdx.x * 64;
    const int tid  = threadIdx.x;

    for (int c = tid; c < 1152; c += 256) {
        int j = c >> 3, kk = (c & 7) * 8;
        *(float4*)&wp_s[j][kk] = *(const float4*)&wp[j * 64 + kk];
    }
    for (int c = tid; c < 512; c += 256) {
        int nl = c >> 3, kk = (c & 7) * 8;
        int n = base + nl;
        _Float16 h8[8];
        if (n < N_) {
            float4 f0 = *(const float4*)&feat[(size_t)n * 64 + kk];
            float4 f1 = *(const float4*)&feat[(size_t)n * 64 + kk + 4];
            h8[0]=(_Float16)f0.x; h8[1]=(_Float16)f0.y; h8[2]=(_Float16)f0.z; h8[3]=(_Float16)f0.w;
            h8[4]=(_Float16)f1.x; h8[5]=(_Float16)f1.y; h8[6]=(_Float16)f1.z; h8[7]=(_Float16)f1.w;
        } else {
#pragma unroll
            for (int q = 0; q < 8; ++q) h8[q] = (_Float16)0.f;
        }
        *(float4*)&fs[nl][kk] = *(float4*)h8;
    }
    __syncthreads();

    const int wv   = tid >> 6;
    const int lane = tid & 63;
    const int rc   = lane & 15;
    const int kh   = lane >> 4;

    f32x4 acc[9];
#pragma unroll
    for (int nt = 0; nt < 9; ++nt) acc[nt] = (f32x4){0.f, 0.f, 0.f, 0.f};

#pragma unroll
    for (int kt = 0; kt < 2; ++kt) {
        f16x8 a = *(const f16x8*)&fs[wv * 16 + rc][kt * 32 + kh * 8];
#pragma unroll
        for (int nt = 0; nt < 9; ++nt) {
            f16x8 bfr = *(const f16x8*)&wp_s[nt * 16 + rc][kt * 32 + kh * 8];
            acc[nt] = __builtin_amdgcn_mfma_f32_16x16x32_f16(a, bfr, acc[nt], 0, 0, 0);
        }
    }

#pragma unroll
    for (int r = 0; r < 4; ++r) {
        int n = base + wv * 16 + kh * 4 + r;
        if (n >= N_) continue;
#pragma unroll
        for (int nt = 0; nt < 8; ++nt)
            xh[(size_t)n * OUT_ + nt * 16 + rc] = __float2half(acc[nt][r]);
        if (rc < 8) asrc[n * H_ + rc] = acc[8][r];
        else        adst[n * H_ + (rc - 8)] = acc[8][r];
    }
}

// K2a: bin edges by dst>>8 into fixed-capacity bucket runs (packed rel|src).
__global__ __launch_bounds__(256) void k_bin(const int* __restrict__ src,
                                             const int* __restrict__ dst,
                                             int* __restrict__ bcnt,
                                             unsigned int* __restrict__ pairs) {
    __shared__ int cnt[NBUCK];
    __shared__ int base[NBUCK];
    const int tid = threadIdx.x;
    for (int i = tid; i < NBUCK; i += 256) cnt[i] = 0;
    __syncthreads();
    const int e0 = blockIdx.x * EPB;
    const int ne = min(EPB, E_ - e0);
    for (int i = tid; i < ne; i += 256) atomicAdd(&cnt[dst[e0 + i] >> 8], 1);
    __syncthreads();
    for (int i = tid; i < NBUCK; i += 256) {
        int c = cnt[i];
        base[i] = (c > 0) ? atomicAdd(&bcnt[i], c) : 0;
        cnt[i] = 0;
    }
    __syncthreads();
    for (int i = tid; i < ne; i += 256) {
        int d = dst[e0 + i];
        int s = src[e0 + i];
        int b = d >> 8;
        int p = base[b] + atomicAdd(&cnt[b], 1);
        pairs[(size_t)b * CAP + p] = ((unsigned int)(d & 255) << 16) | (unsigned int)s;
    }
}

// K2b: exclusive scan of bucket counts -> bstart[NBUCK+1].
__global__ void k_scanb(const int* __restrict__ bcnt, int* __restrict__ bstart) {
    __shared__ int s[256];
    int t = threadIdx.x;
    int v = (t < NBUCK) ? bcnt[t] : 0;
    s[t] = v;
    __syncthreads();
    for (int off = 1; off < 256; off <<= 1) {
        int u = (t >= off) ? s[t - off] : 0;
        __syncthreads();
        s[t] += u;
        __syncthreads();
    }
    if (t < NBUCK) bstart[t] = s[t] - v;
    if (t == NBUCK - 1) bstart[NBUCK] = s[t];
}

// K2c: per-bucket local hist+scan -> rowstart; scatter eidx via LDS cursors.
__global__ __launch_bounds__(256) void k_scat3(const unsigned int* __restrict__ pairs,
                                               const int* __restrict__ bcnt,
                                               const int* __restrict__ bstart,
                                               int* __restrict__ rowstart,
                                               int* __restrict__ eidx) {
    __shared__ int cnt[256];
    __shared__ int s[256];
    __shared__ int cur[256];
    const int b  = blockIdx.x;
    const int t  = threadIdx.x;
    const int nb = bcnt[b];
    const size_t p0 = (size_t)b * CAP;

    cnt[t] = 0;
    __syncthreads();
    for (int i = t; i < nb; i += 256)
        atomicAdd(&cnt[pairs[p0 + i] >> 16], 1);
    __syncthreads();
    int v = cnt[t];
    s[t] = v;
    __syncthreads();
    for (int off = 1; off < 256; off <<= 1) {
        int u = (t >= off) ? s[t - off] : 0;
        __syncthreads();
        s[t] += u;
        __syncthreads();
    }
    int rs = bstart[b] + s[t] - v;   // exclusive
    int n = b * 256 + t;
    if (n < N_) rowstart[n] = rs;
    if (b == NBUCK - 1 && t == 0) rowstart[N_] = E_;
    cur[t] = rs;
    __syncthreads();
    for (int i = t; i < nb; i += 256) {
        unsigned int pk = pairs[p0 + i];
        int d = (int)(pk >> 16);
        int pos = atomicAdd(&cur[d], 1);
        eidx[pos] = (int)(pk & 0xFFFFu);
    }
}

// K3: CSR aggregation (4-edge unroll; gathers independent of exp chain).
__global__ void k_agg(const int* __restrict__ rowstart, const int* __restrict__ eidx,
                      const __half* __restrict__ xh, const float* __restrict__ asrc,
                      const float* __restrict__ adst, const float* __restrict__ bias,
                      __half* __restrict__ embh) {
    const int dn   = blockIdx.x * 4 + (threadIdx.x >> 6);
    const int lane = threadIdx.x & 63;
    const int h    = lane >> 3;
    const float adst_h = adst[dn * H_ + h];
    const uint choff = (uint)lane * 2;

    const int beg = rowstart[dn];
    const int end = rowstart[dn + 1];

    float ax = 0.f, ay = 0.f, sw = 0.f;
    int i = beg;
    for (; i + 3 < end; i += 4) {
        int s0 = eidx[i];
        int s1 = eidx[i + 1];
        int s2 = eidx[i + 2];
        int s3 = eidx[i + 3];
        __half2 x0 = *(const __half2*)(xh + ((uint)s0 * OUT_ + choff));
        __half2 x1 = *(const __half2*)(xh + ((uint)s1 * OUT_ + choff));
        __half2 x2 = *(const __half2*)(xh + ((uint)s2 * OUT_ + choff));
        __half2 x3 = *(const __half2*)(xh + ((uint)s3 * OUT_ + choff));
        float a0 = asrc[(uint)s0 * H_ + h] + adst_h;
        float a1 = asrc[(uint)s1 * H_ + h] + adst_h;
        float a2 = asrc[(uint)s2 * H_ + h] + adst_h;
        float a3 = asrc[(uint)s3 * H_ + h] + adst_h;
        a0 = (a0 > 0.f) ? a0 : NEG_SLOPE * a0;
        a1 = (a1 > 0.f) ? a1 : NEG_SLOPE * a1;
        a2 = (a2 > 0.f) ? a2 : NEG_SLOPE * a2;
        a3 = (a3 > 0.f) ? a3 : NEG_SLOPE * a3;
        float w0 = __expf(a0);
        float w1 = __expf(a1);
        float w2 = __expf(a2);
        float w3 = __expf(a3);
        float2 f0 = __half22float2(x0);
        float2 f1 = __half22float2(x1);
        float2 f2 = __half22float2(x2);
        float2 f3 = __half22float2(x3);
        ax = fmaf(w0, f0.x, fmaf(w1, f1.x, fmaf(w2, f2.x, fmaf(w3, f3.x, ax))));
        ay = fmaf(w0, f0.y, fmaf(w1, f1.y, fmaf(w2, f2.y, fmaf(w3, f3.y, ay))));
        sw += (w0 + w1) + (w2 + w3);
    }
    for (; i < end; ++i) {
        int s0 = eidx[i];
        __half2 x0 = *(const __half2*)(xh + ((uint)s0 * OUT_ + choff));
        float a0 = asrc[(uint)s0 * H_ + h] + adst_h;
        a0 = (a0 > 0.f) ? a0 : NEG_SLOPE * a0;
        float w0 = __expf(a0);
        float2 f0 = __half22float2(x0);
        ax = fmaf(w0, f0.x, ax);
        ay = fmaf(w0, f0.y, ay);
        sw += w0;
    }
    {
        float al = asrc[(uint)dn * H_ + h] + adst_h;
        al = (al > 0.f) ? al : NEG_SLOPE * al;
        float w = __expf(al);
        __half2 xv = *(const __half2*)(xh + ((uint)dn * OUT_ + choff));
        float2 fv = __half22float2(xv);
        ax = fmaf(w, fv.x, ax);
        ay = fmaf(w, fv.y, ay);
        sw += w;
    }
    float ox = ax / sw + bias[lane * 2];
    float oy = ay / sw + bias[lane * 2 + 1];
    ox = (ox > 0.f) ? ox : expm1f(ox);
    oy = (oy > 0.f) ? oy : expm1f(oy);
    *(__half2*)&embh[(size_t)dn * OUT_ + lane * 2] = __floats2half2_rn(ox, oy);
}

// K5: mean-pool numerator from f16 emb. 64 nodes/block, 16-node runs.
__global__ void k_pool(const __half* __restrict__ embh, const int* __restrict__ batch,
                       float* __restrict__ gsum) {
    int c   = threadIdx.x & 63;
    int grp = threadIdx.x >> 6;
    int base = blockIdx.x * 64 + grp * 16;
    float rx = 0.f, ry = 0.f;
    int gcur = -1;
    for (int i = 0; i < 16; ++i) {
        int n = base + i;
        if (n >= N_) break;
        int g = batch[n];
        if (g != gcur) {
            if (gcur >= 0) {
                unsafeAtomicAdd(&gsum[gcur * OUT_ + 2 * c], rx);
                unsafeAtomicAdd(&gsum[gcur * OUT_ + 2 * c + 1], ry);
            }
            gcur = g; rx = ry = 0.f;
        }
        __half2 v = *(const __half2*)&embh[(size_t)n * OUT_ + 2 * c];
        float2 f = __half22float2(v);
        rx += f.x; ry += f.y;
    }
    if (gcur >= 0) {
        unsafeAtomicAdd(&gsum[gcur * OUT_ + 2 * c], rx);
        unsafeAtomicAdd(&gsum[gcur * OUT_ + 2 * c + 1], ry);
    }
}

// K6: fused per-graph: count, gemb -> output, gpart = gemb @ W1b + b1.
__global__ void k_graph(const int* __restrict__ batch, const float* __restrict__ gsum,
                        const float* __restrict__ W1, const float* __restrict__ b1,
                        float* __restrict__ outg, float* __restrict__ gpart) {
    const int g = blockIdx.x;
    const int j = threadIdx.x;
    __shared__ float ge[128];
    __shared__ int cnt_s;
    if (j == 0) {
        int lo = 0, hi = N_;
        while (lo < hi) { int m = (lo + hi) >> 1; if (batch[m] < g) lo = m + 1; else hi = m; }
        int start = lo;
        lo = 0; hi = N_;
        while (lo < hi) { int m = (lo + hi) >> 1; if (batch[m] <= g) lo = m + 1; else hi = m; }
        cnt_s = lo - start;
    }
    __syncthreads();
    float v = gsum[g * 128 + j] / fmaxf((float)cnt_s, 1.f);
    ge[j] = v;
    outg[g * 128 + j] = v;
    __syncthreads();
    float s = b1[j];
    const float* w = W1 + (size_t)128 * 128 + j;
    for (int k = 0; k < 128; ++k) s = fmaf(ge[k], w[(size_t)k * 128], s);
    gpart[g * 128 + j] = s;
}

// K7: MFMA decoder. 64 nodes/block, 4 waves.
__global__ __launch_bounds__(256) void k_dec3(const __half* __restrict__ embh,
                                              const __half* __restrict__ wtg,
                                              const float* __restrict__ gpart,
                                              const int* __restrict__ batch,
                                              const float* __restrict__ W2,
                                              const float* __restrict__ b2,
                                              float* __restrict__ scores) {
    __shared__ _Float16 wt_s[128][128];
    __shared__ _Float16 emb_s[64][128];
    __shared__ float    w2_s[128];
    const int base = blockIdx.x * 64;
    const int tid  = threadIdx.x;

    for (int c = tid; c < 2048; c += 256) {
        int j = c >> 4, kk = (c & 15) * 8;
        *(float4*)&wt_s[j][kk] = *(const float4*)&wtg[j * 128 + kk];
    }
    for (int c = tid; c < 1024; c += 256) {
        int nl = c >> 4, kk = (c & 15) * 8;
        int n = base + nl;
        if (n < N_)
            *(float4*)&emb_s[nl][kk] = *(const float4*)&embh[(size_t)n * 128 + kk];
        else
            *(float4*)&emb_s[nl][kk] = make_float4(0.f, 0.f, 0.f, 0.f);
    }
    if (tid < 128) w2_s[tid] = W2[tid];
    __syncthreads();

    const int wv   = tid >> 6;
    const int lane = tid & 63;
    const int rc   = lane & 15;
    const int kh   = lane >> 4;

    f32x4 acc[8];
#pragma unroll
    for (int nt = 0; nt < 8; ++nt) acc[nt] = (f32x4){0.f, 0.f, 0.f, 0.f};

#pragma unroll
    for (int kt = 0; kt < 4; ++kt) {
        f16x8 a = *(const f16x8*)&emb_s[wv * 16 + rc][kt * 32 + kh * 8];
#pragma unroll
        for (int nt = 0; nt < 8; ++nt) {
            f16x8 bfr = *(const f16x8*)&wt_s[nt * 16 + rc][kt * 32 + kh * 8];
            acc[nt] = __builtin_amdgcn_mfma_f32_16x16x32_f16(a, bfr, acc[nt], 0, 0, 0);
        }
    }

    const float b2v = b2[0];
    float s[4] = {0.f, 0.f, 0.f, 0.f};
    int   gi[4];
#pragma unroll
    for (int r = 0; r < 4; ++r) {
        int n = base + wv * 16 + kh * 4 + r;
        gi[r] = (n < N_) ? batch[n] : 0;
    }
#pragma unroll
    for (int nt = 0; nt < 8; ++nt) {
        int j = nt * 16 + rc;
        float w2 = w2_s[j];
#pragma unroll
        for (int r = 0; r < 4; ++r) {
            float hv = acc[nt][r] + gpart[(size_t)gi[r] * 128 + j];
            hv = (hv > 0.f) ? hv : 0.f;
            s[r] = fmaf(hv, w2, s[r]);
        }
    }
#pragma unroll
    for (int r = 0; r < 4; ++r) {
#pragma unroll
        for (int m = 8; m >= 1; m >>= 1) s[r] += __shfl_xor(s[r], m, 16);
    }
    if (rc == 0) {
#pragma unroll
        for (int r = 0; r < 4; ++r) {
            int n = base + wv * 16 + kh * 4 + r;
            if (n < N_) scores[n] = s[r] + b2v;
        }
    }
}

extern "C" void kernel_launch(void* const* d_in, const int* in_sizes, int n_in,
                              void* d_out, int out_size, void* d_ws, size_t ws_size,
                              hipStream_t stream) {
    const float* feat   = (const float*)d_in[0];
    const int*   ei     = (const int*)d_in[1];
    const int*   batch  = (const int*)d_in[2];
    const float* Wg     = (const float*)d_in[3];
    const float* att_s  = (const float*)d_in[4];
    const float* att_d  = (const float*)d_in[5];
    const float* bias_g = (const float*)d_in[6];
    const float* W1     = (const float*)d_in[7];
    const float* b1     = (const float*)d_in[8];
    const float* W2     = (const float*)d_in[9];
    const float* b2     = (const float*)d_in[10];
    char*  wsb = (char*)d_ws;
    float* out = (float*)d_out;

    const int* src = ei;        // edge_index[0]
    const int* dst = ei + E_;   // edge_index[1]

    __half* XH    = (__half*)(wsb + OFF_X);
    __half* EMBH  = (__half*)(wsb + OFF_EMBH);
    float*  ASRC  = (float*)(wsb + OFF_ASRC);
    float*  ADST  = (float*)(wsb + OFF_ADST);
    unsigned int* PAIRS = (unsigned int*)(wsb + OFF_PAIRS);
    float*  GSUM  = (float*)(wsb + OFF_GSUM);
    int*    BCNT  = (int*)  (wsb + OFF_BCNT);
    __half* WT    = (__half*)(wsb + OFF_WT);
    __half* WP    = (__half*)(wsb + OFF_WP);
    int*    BSTART= (int*)  (wsb + OFF_BSTART);
    int*    ROWS  = (int*)  (wsb + OFF_ROWS);
    int*    EIDX  = (int*)  (wsb + OFF_EIDX);
    float*  GPART = (float*)(wsb + OFF_GPART);

    hipMemsetAsync(wsb + ZERO_BEG, 0, ZERO_LEN, stream);

    k_prep<<<17, 256, 0, stream>>>(Wg, att_s, att_d, W1, WP, WT);
    k_bin<<<(E_ + EPB - 1) / EPB, 256, 0, stream>>>(src, dst, BCNT, PAIRS);
    k_scanb<<<1, 256, 0, stream>>>(BCNT, BSTART);
    k_scat3<<<NBUCK, 256, 0, stream>>>(PAIRS, BCNT, BSTART, ROWS, EIDX);
    k_xform<<<(N_ + 63) / 64, 256, 0, stream>>>(feat, WP, XH, ASRC, ADST);
    k_agg<<<N_ / 4, 256, 0, stream>>>(ROWS, EIDX, XH, ASRC, ADST, bias_g, EMBH);
    k_pool<<<(N_ + 63) / 64, 256, 0, stream>>>(EMBH, batch, GSUM);
    k_graph<<<G_, 128, 0, stream>>>(batch, GSUM, W1, b1, out + N_, GPART);
    k_dec3<<<(N_ + 63) / 64, 256, 0, stream>>>(EMBH, WT, GPART, batch, W2, b2, out);
}